// Round 1
// baseline (3945.414 us; speedup 1.0000x reference)
//
#include <hip/hip_runtime.h>
#include <hip/hip_bf16.h>

#define BB  512
#define TT  128
#define CC  96
#define HH  6
#define HSZ 16
#define LL  6
#define FFD 384
#define VV  65
#define BT  (BB * TT)   // 65536 rows

// ---------------- embedding: x[b,t,:] = tok_emb[idx[b,t],:] + pos_emb[t,:] ----------------
__global__ __launch_bounds__(256) void embed_kernel(
    const int* __restrict__ idx, const float* __restrict__ tok,
    const float* __restrict__ pos, float* __restrict__ x) {
  int gid = blockIdx.x * 256 + threadIdx.x;      // over BT*24 float4s
  int r = gid / 24, c4 = gid % 24;
  int t = r & (TT - 1);
  int token = idx[r];
  const float4 a = *(const float4*)&tok[token * CC + c4 * 4];
  const float4 p = *(const float4*)&pos[t * CC + c4 * 4];
  float4 o;
  o.x = a.x + p.x; o.y = a.y + p.y; o.z = a.z + p.z; o.w = a.w + p.w;
  *(float4*)&x[(size_t)r * CC + c4 * 4] = o;
}

// ---------------- layernorm over rows of 96: 32 lanes/row, 8 rows/block ----------------
__global__ __launch_bounds__(256) void ln_kernel(
    const float* __restrict__ in, float* __restrict__ out,
    const float* __restrict__ g, const float* __restrict__ b) {
  int lane = threadIdx.x & 31;
  int r8 = threadIdx.x >> 5;
  size_t row = (size_t)blockIdx.x * 8 + r8;
  const float* p = in + row * CC;
  float v0 = p[lane], v1 = p[lane + 32], v2 = p[lane + 64];
  float s = v0 + v1 + v2;
  float s2 = v0 * v0 + v1 * v1 + v2 * v2;
#pragma unroll
  for (int m = 16; m; m >>= 1) {
    s  += __shfl_xor(s,  m, 32);
    s2 += __shfl_xor(s2, m, 32);
  }
  float mean = s * (1.f / 96.f);
  float var  = s2 * (1.f / 96.f) - mean * mean;
  float rs = rsqrtf(var + 1e-5f);
  float* q = out + row * CC;
  q[lane]      = (v0 - mean) * rs * g[lane]      + b[lane];
  q[lane + 32] = (v1 - mean) * rs * g[lane + 32] + b[lane + 32];
  q[lane + 64] = (v2 - mean) * rs * g[lane + 64] + b[lane + 64];
}

// ---------------- generic tall-skinny fp32 GEMM ----------------
// out[r][n] = act( sum_k A[r][k] * W[k][n] + bias[n] ) (+ res[r][n])
// WMODE 0: W row-major [K][N].  WMODE 1: per-head QKV weight [H][C][HS], col n = h*16+d.
template<int KTOT, int N, int WMODE, bool BIAS, bool RELU, bool RESADD>
__global__ __launch_bounds__(256) void gemm_kernel(
    const float* __restrict__ A, const float* __restrict__ W,
    const float* __restrict__ bias, const float* __restrict__ res,
    float* __restrict__ out) {
  __shared__ float As[64][100];   // 64 rows x 96, pad to 100 (400B row = 16B-mult, banks spread)
  __shared__ float Ws[96][64];
  const int tx = threadIdx.x & 15;   // col group -> cols tx*4..+3
  const int ty = threadIdx.x >> 4;   // row group -> rows ty*4..+3
  const int row0 = blockIdx.x * 64;
  const int n0 = blockIdx.y * 64;
  float acc[4][4] = {};
  for (int kc = 0; kc < KTOT; kc += 96) {
    // stage A tile (coalesced float4)
#pragma unroll
    for (int it = 0; it < 6; ++it) {
      int f4 = threadIdx.x + it * 256;            // 0..1535
      int r = f4 / 24, c4 = f4 % 24;
      const float4 vA = *(const float4*)&A[(size_t)(row0 + r) * KTOT + kc + c4 * 4];
      *(float4*)&As[r][c4 * 4] = vA;
    }
    // stage W tile (zero-pad cols beyond N)
#pragma unroll
    for (int it = 0; it < 24; ++it) {
      int f = threadIdx.x + it * 256;             // 0..6143
      int k = f >> 6, n = f & 63;
      int nn = n0 + n;
      float w = 0.f;
      if (nn < N) {
        if (WMODE == 0) w = W[(size_t)(kc + k) * N + nn];
        else            w = W[((nn >> 4) * CC + kc + k) * HSZ + (nn & 15)];
      }
      Ws[k][n] = w;
    }
    __syncthreads();
#pragma unroll 8
    for (int k = 0; k < 96; ++k) {
      const float4 wv = *(const float4*)&Ws[k][tx * 4];
      float a0 = As[ty * 4 + 0][k];
      float a1 = As[ty * 4 + 1][k];
      float a2 = As[ty * 4 + 2][k];
      float a3 = As[ty * 4 + 3][k];
      acc[0][0] += a0 * wv.x; acc[0][1] += a0 * wv.y; acc[0][2] += a0 * wv.z; acc[0][3] += a0 * wv.w;
      acc[1][0] += a1 * wv.x; acc[1][1] += a1 * wv.y; acc[1][2] += a1 * wv.z; acc[1][3] += a1 * wv.w;
      acc[2][0] += a2 * wv.x; acc[2][1] += a2 * wv.y; acc[2][2] += a2 * wv.z; acc[2][3] += a2 * wv.w;
      acc[3][0] += a3 * wv.x; acc[3][1] += a3 * wv.y; acc[3][2] += a3 * wv.z; acc[3][3] += a3 * wv.w;
    }
    __syncthreads();
  }
#pragma unroll
  for (int i = 0; i < 4; ++i) {
    size_t r = row0 + ty * 4 + i;
#pragma unroll
    for (int j = 0; j < 4; ++j) {
      int n = n0 + tx * 4 + j;
      if (N % 64 == 0 || n < N) {
        float v_ = acc[i][j];
        if (BIAS)   v_ += bias[n];
        if (RELU)   v_ = fmaxf(v_, 0.f);
        if (RESADD) v_ += res[r * N + n];
        out[r * N + n] = v_;
      }
    }
  }
}

// ---------------- causal attention: one block per (b, h, 64-row half) ----------------
__global__ __launch_bounds__(256) void attn_kernel(
    const float* __restrict__ q, const float* __restrict__ k,
    const float* __restrict__ v, float* __restrict__ o) {
  int bid = blockIdx.x;
  int half = bid & 1;
  int bh = bid >> 1;
  int b = bh / HH, h = bh % HH;
  const size_t base = (size_t)b * TT * CC + h * HSZ;   // q/k/v/o stored as [B,T,H*HS]

  __shared__ float qs[64][17];
  __shared__ float ks[TT][17];
  __shared__ float vs[TT][17];
  __shared__ float S[64][132];

  // stage K, V (full 128 rows), Q (this block's 64 rows)
  for (int it = 0; it < 8; ++it) {
    int f = threadIdx.x + it * 256;   // 0..2047
    int t = f >> 4, d = f & 15;
    ks[t][d] = k[base + (size_t)t * CC + d];
    vs[t][d] = v[base + (size_t)t * CC + d];
  }
  for (int it = 0; it < 4; ++it) {
    int f = threadIdx.x + it * 256;   // 0..1023
    int t = f >> 4, d = f & 15;
    qs[t][d] = q[base + (size_t)(half * 64 + t) * CC + d];
  }
  __syncthreads();

  // S = scale * Q K^T  (64x128), thread tile 4 rows x 8 cols
  {
    int ti = threadIdx.x >> 4;   // rows ti*4..+3
    int tj = threadIdx.x & 15;   // cols tj*8..+7
    float acc[4][8] = {};
#pragma unroll
    for (int d = 0; d < 16; ++d) {
      float a0 = qs[ti * 4 + 0][d];
      float a1 = qs[ti * 4 + 1][d];
      float a2 = qs[ti * 4 + 2][d];
      float a3 = qs[ti * 4 + 3][d];
      float bb[8];
#pragma unroll
      for (int j = 0; j < 8; ++j) bb[j] = ks[tj * 8 + j][d];
#pragma unroll
      for (int j = 0; j < 8; ++j) {
        acc[0][j] += a0 * bb[j];
        acc[1][j] += a1 * bb[j];
        acc[2][j] += a2 * bb[j];
        acc[3][j] += a3 * bb[j];
      }
    }
    const float scale = 0.25f;   // HS^-0.5
#pragma unroll
    for (int i = 0; i < 4; ++i)
#pragma unroll
      for (int j = 0; j < 8; ++j)
        S[ti * 4 + i][tj * 8 + j] = acc[i][j] * scale;
  }
  __syncthreads();

  // causal softmax, one thread per row
  if (threadIdx.x < 64) {
    int r = threadIdx.x;
    int rg = half * 64 + r;       // global row index = causal bound
    float m = -1e30f;
    for (int j = 0; j <= rg; ++j) m = fmaxf(m, S[r][j]);
    float sum = 0.f;
    for (int j = 0; j <= rg; ++j) { float p = __expf(S[r][j] - m); S[r][j] = p; sum += p; }
    float inv = 1.f / sum;
    for (int j = 0; j <= rg; ++j) S[r][j] *= inv;
    for (int j = rg + 1; j < TT; ++j) S[r][j] = 0.f;
  }
  __syncthreads();

  // O = P V  (64x16): thread owns (4 rows, 1 dim)
  {
    int d = threadIdx.x & 15;
    int i0 = (threadIdx.x >> 4) * 4;
    float oc[4] = {};
    for (int j = 0; j < TT; ++j) {
      float vv = vs[j][d];
#pragma unroll
      for (int i = 0; i < 4; ++i) oc[i] += S[i0 + i][j] * vv;
    }
#pragma unroll
    for (int i = 0; i < 4; ++i)
      o[base + (size_t)(half * 64 + i0 + i) * CC + d] = oc[i];
  }
}

extern "C" void kernel_launch(void* const* d_in, const int* in_sizes, int n_in,
                              void* d_out, int out_size, void* d_ws, size_t ws_size,
                              hipStream_t stream) {
  const int*   idx  = (const int*)d_in[0];
  const float* tok  = (const float*)d_in[1];
  const float* pos  = (const float*)d_in[2];
  const float* Wq   = (const float*)d_in[3];
  const float* Wk   = (const float*)d_in[4];
  const float* Wv   = (const float*)d_in[5];
  const float* Wp   = (const float*)d_in[6];
  const float* bp   = (const float*)d_in[7];
  const float* W1   = (const float*)d_in[8];
  const float* b1   = (const float*)d_in[9];
  const float* W2   = (const float*)d_in[10];
  const float* b2   = (const float*)d_in[11];
  const float* ln1g = (const float*)d_in[12];
  const float* ln1b = (const float*)d_in[13];
  const float* ln2g = (const float*)d_in[14];
  const float* ln2b = (const float*)d_in[15];
  const float* lnfg = (const float*)d_in[16];
  const float* lnfb = (const float*)d_in[17];
  const float* Wlm  = (const float*)d_in[18];
  const float* blm  = (const float*)d_in[19];

  // workspace layout (fp32): x | h | shared region (qkv or ff1 output)
  float* x    = (float*)d_ws;
  float* hbuf = x + (size_t)BT * CC;
  float* sbuf = hbuf + (size_t)BT * CC;
  float* qb = sbuf;
  float* kb = sbuf + (size_t)BT * CC;
  float* vb = sbuf + 2 * (size_t)BT * CC;
  float* fbuf = sbuf;                         // BT*FFD, overlaps q/k/v (disjoint lifetimes)

  embed_kernel<<<BT * 24 / 256, 256, 0, stream>>>(idx, tok, pos, x);

  for (int l = 0; l < LL; ++l) {
    ln_kernel<<<BT / 8, 256, 0, stream>>>(x, hbuf, ln1g + l * CC, ln1b + l * CC);
    gemm_kernel<96, 96, 1, false, false, false>
        <<<dim3(BT / 64, 2), 256, 0, stream>>>(hbuf, Wq + l * HH * CC * HSZ, nullptr, nullptr, qb);
    gemm_kernel<96, 96, 1, false, false, false>
        <<<dim3(BT / 64, 2), 256, 0, stream>>>(hbuf, Wk + l * HH * CC * HSZ, nullptr, nullptr, kb);
    gemm_kernel<96, 96, 1, false, false, false>
        <<<dim3(BT / 64, 2), 256, 0, stream>>>(hbuf, Wv + l * HH * CC * HSZ, nullptr, nullptr, vb);
    attn_kernel<<<BB * HH * 2, 256, 0, stream>>>(qb, kb, vb, hbuf);   // o -> hbuf
    gemm_kernel<96, 96, 0, true, false, true>
        <<<dim3(BT / 64, 2), 256, 0, stream>>>(hbuf, Wp + l * CC * CC, bp + l * CC, x, x);
    ln_kernel<<<BT / 8, 256, 0, stream>>>(x, hbuf, ln2g + l * CC, ln2b + l * CC);
    gemm_kernel<96, 384, 0, true, true, false>
        <<<dim3(BT / 64, 6), 256, 0, stream>>>(hbuf, W1 + l * CC * FFD, b1 + l * FFD, nullptr, fbuf);
    gemm_kernel<384, 96, 0, true, false, true>
        <<<dim3(BT / 64, 2), 256, 0, stream>>>(fbuf, W2 + l * FFD * CC, b2 + l * CC, x, x);
  }

  ln_kernel<<<BT / 8, 256, 0, stream>>>(x, hbuf, lnfg, lnfb);
  gemm_kernel<96, 65, 0, true, false, false>
      <<<dim3(BT / 64, 2), 256, 0, stream>>>(hbuf, Wlm, blm, nullptr, (float*)d_out);
}

// Round 6
// 1497.621 us; speedup vs baseline: 2.6345x; 2.6345x over previous
//
#include <hip/hip_runtime.h>
#include <hip/hip_bf16.h>

#define BB  512
#define TT  128
#define CC  96
#define HH  6
#define HSZ 16
#define LL  6
#define FFD 384
#define VV  65
#define BT  (BB * TT)   // 65536 rows

using short8 = __attribute__((ext_vector_type(8))) short;   // 8 bf16 (4 VGPRs)
using f32x4  = __attribute__((ext_vector_type(4))) float;

static __device__ __forceinline__ unsigned short f2bf(float f) {
  union { float f; unsigned u; } v{f};
  unsigned r = (v.u + 0x7fff + ((v.u >> 16) & 1)) >> 16;   // RNE
  return (unsigned short)r;
}
static __device__ __forceinline__ float b2f(unsigned short h) {
  union { unsigned u; float f; } v{(unsigned)h << 16};
  return v.f;
}

// ---------------- embedding: x[b,t,:] = tok_emb[idx[b,t],:] + pos_emb[t,:] (fp32) -------
__global__ __launch_bounds__(256) void embed_kernel(
    const int* __restrict__ idx, const float* __restrict__ tok,
    const float* __restrict__ pos, float* __restrict__ x) {
  int gid = blockIdx.x * 256 + threadIdx.x;      // over BT*24 float4s
  int r = gid / 24, c4 = gid % 24;
  int t = r & (TT - 1);
  int token = idx[r];
  const float4 a = *(const float4*)&tok[token * CC + c4 * 4];
  const float4 p = *(const float4*)&pos[t * CC + c4 * 4];
  float4 o;
  o.x = a.x + p.x; o.y = a.y + p.y; o.z = a.z + p.z; o.w = a.w + p.w;
  *(float4*)&x[(size_t)r * CC + c4 * 4] = o;
}

// ---------------- layernorm fp32 in -> bf16 out: 32 lanes/row, 8 rows/block -------------
__global__ __launch_bounds__(256) void ln_kernel(
    const float* __restrict__ in, unsigned short* __restrict__ out,
    const float* __restrict__ g, const float* __restrict__ b) {
  int lane = threadIdx.x & 31;
  int r8 = threadIdx.x >> 5;
  size_t row = (size_t)blockIdx.x * 8 + r8;
  const float* p = in + row * CC;
  float v0 = p[lane], v1 = p[lane + 32], v2 = p[lane + 64];
  float s = v0 + v1 + v2;
  float s2 = v0 * v0 + v1 * v1 + v2 * v2;
#pragma unroll
  for (int m = 16; m; m >>= 1) {
    s  += __shfl_xor(s,  m, 32);
    s2 += __shfl_xor(s2, m, 32);
  }
  float mean = s * (1.f / 96.f);
  float var  = s2 * (1.f / 96.f) - mean * mean;
  float rs = rsqrtf(var + 1e-5f);
  unsigned short* q = out + row * CC;
  q[lane]      = f2bf((v0 - mean) * rs * g[lane]      + b[lane]);
  q[lane + 32] = f2bf((v1 - mean) * rs * g[lane + 32] + b[lane + 32]);
  q[lane + 64] = f2bf((v2 - mean) * rs * g[lane + 64] + b[lane + 64]);
}

// ---------------- weight pack: fp32 -> bf16 fragment-major [cb][ks][lane][8] ------------
// b_frag element j of lane l == B[k = ks*32 + (l>>4)*8 + j][n = cb*16 + (l&15)]
__global__ __launch_bounds__(256) void pack_w(
    const float* __restrict__ Wq, const float* __restrict__ Wk,
    const float* __restrict__ Wv, const float* __restrict__ Wp,
    const float* __restrict__ W1, const float* __restrict__ W2,
    const float* __restrict__ Wlm, unsigned short* __restrict__ out) {
  int job = blockIdx.y;
  int e = blockIdx.x * 256 + threadIdx.x;
  int K, sz; size_t obase;
  if (job < 6)       { K = 96;  sz = 27648; obase = (size_t)job * 27648; }
  else if (job < 12) { K = 96;  sz = 9216;  obase = 165888 + (size_t)(job - 6) * 9216; }
  else if (job < 18) { K = 96;  sz = 36864; obase = 221184 + (size_t)(job - 12) * 36864; }
  else if (job < 24) { K = 384; sz = 36864; obase = 442368 + (size_t)(job - 18) * 36864; }
  else               { K = 96;  sz = 7680;  obase = 663552; }
  if (e >= sz) return;
  int j = e & 7, lane = (e >> 3) & 63, rest = e >> 9;
  int KS = K / 32;
  int ks = rest % KS, cb = rest / KS;
  int k = ks * 32 + (lane >> 4) * 8 + j;
  int n = cb * 16 + (lane & 15);
  float val = 0.f;
  if (job < 6) {              // fused QKV, N=288: [H][C][HS] per source
    int src = n / 96, nn = n % 96;
    const float* W = (src == 0) ? Wq : (src == 1) ? Wk : Wv;
    val = W[((size_t)(job * 6 + (nn >> 4)) * 96 + k) * 16 + (nn & 15)];
  } else if (job < 12) {      // proj [96][96]
    val = Wp[(size_t)(job - 6) * 9216 + k * 96 + n];
  } else if (job < 18) {      // ff1 [96][384]
    val = W1[(size_t)(job - 12) * 36864 + k * 384 + n];
  } else if (job < 24) {      // ff2 [384][96]
    val = W2[(size_t)(job - 18) * 36864 + k * 96 + n];
  } else {                    // lm head [96][65] padded to N=80
    if (n < 65) val = Wlm[k * 65 + n];
  }
  out[obase + e] = f2bf(val);
}

// ---------------- MFMA GEMM: out[r][n] = act(sum_k A[r][k]*W[k][n] + bias) (+res) -------
// A: bf16 row-major [BT][K]. W: packed frags. 256 thr = 4 waves, each wave 16 rows.
template<int K, int N, int NS, bool BIAS, bool RELU, bool RES, bool OUTBF>
__global__ __launch_bounds__(256) void mfma_gemm(
    const unsigned short* __restrict__ A, const unsigned short* __restrict__ Wpk,
    const float* __restrict__ bias, const float* __restrict__ res, void* __restrict__ out) {
  constexpr int KS = K / 32;
  const int lane = threadIdx.x & 63;
  const int wave = threadIdx.x >> 6;
  const int r0 = blockIdx.x * 64 + wave * 16;
  const int c15 = lane & 15, kg = lane >> 4;
  short8 a[KS];
  const unsigned short* ap = A + (size_t)(r0 + c15) * K + kg * 8;
#pragma unroll
  for (int ks = 0; ks < KS; ++ks) a[ks] = *(const short8*)(ap + ks * 32);
  const short8* wf = (const short8*)Wpk;
#pragma unroll 1
  for (int cb = 0; cb < N / 16; ++cb) {
    f32x4 acc = {0.f, 0.f, 0.f, 0.f};
#pragma unroll
    for (int ks = 0; ks < KS; ++ks) {
      short8 b = wf[(cb * KS + ks) * 64 + lane];
      acc = __builtin_amdgcn_mfma_f32_16x16x32_bf16(a[ks], b, acc, 0, 0, 0);
    }
    int n = cb * 16 + c15;
#pragma unroll
    for (int i = 0; i < 4; ++i) {
      int row = r0 + kg * 4 + i;
      if (NS == N || n < NS) {
        float v = acc[i];
        if (BIAS) v += bias[n];
        if (RELU) v = fmaxf(v, 0.f);
        if (RES)  v += res[(size_t)row * NS + n];
        if (OUTBF) ((unsigned short*)out)[(size_t)row * NS + n] = f2bf(v);
        else       ((float*)out)[(size_t)row * NS + n] = v;
      }
    }
  }
}

// ---------------- attention: one block per (b,head); scores in registers ----------------
// thread t: row r = t>>1, half hf = t&1 (cols hf*64..hf*64+63). fp32 compute, bf16 I/O.
__global__ __launch_bounds__(256) void attn_kernel(
    const unsigned short* __restrict__ qkv, unsigned short* __restrict__ aout) {
  const int b = blockIdx.x / HH, hd = blockIdx.x % HH;
  __shared__ float ks_[TT][20];
  __shared__ float vs_[TT][20];
  const size_t rowbase = (size_t)b * TT * 288;
  const int coff = hd * HSZ;

  const int r = threadIdx.x >> 1, hf = threadIdx.x & 1;

  // stage K,V rows (each thread: one row, one 8-elem part)
  {
    const unsigned short* kp = qkv + rowbase + (size_t)r * 288 + 96 + coff + hf * 8;
    const unsigned short* vp = kp + 96;
    short8 k8 = *(const short8*)kp;
    short8 v8 = *(const short8*)vp;
    float4 klo, khi, vlo, vhi;
    klo.x = b2f((unsigned short)k8[0]); klo.y = b2f((unsigned short)k8[1]);
    klo.z = b2f((unsigned short)k8[2]); klo.w = b2f((unsigned short)k8[3]);
    khi.x = b2f((unsigned short)k8[4]); khi.y = b2f((unsigned short)k8[5]);
    khi.z = b2f((unsigned short)k8[6]); khi.w = b2f((unsigned short)k8[7]);
    vlo.x = b2f((unsigned short)v8[0]); vlo.y = b2f((unsigned short)v8[1]);
    vlo.z = b2f((unsigned short)v8[2]); vlo.w = b2f((unsigned short)v8[3]);
    vhi.x = b2f((unsigned short)v8[4]); vhi.y = b2f((unsigned short)v8[5]);
    vhi.z = b2f((unsigned short)v8[6]); vhi.w = b2f((unsigned short)v8[7]);
    *(float4*)&ks_[r][hf * 8]     = klo;
    *(float4*)&ks_[r][hf * 8 + 4] = khi;
    *(float4*)&vs_[r][hf * 8]     = vlo;
    *(float4*)&vs_[r][hf * 8 + 4] = vhi;
  }
  // Q row into registers (both hf threads load the same row)
  float q[16];
  {
    const unsigned short* qp = qkv + rowbase + (size_t)r * 288 + coff;
    short8 q0 = *(const short8*)qp;
    short8 q1 = *(const short8*)(qp + 8);
#pragma unroll
    for (int d = 0; d < 8; ++d) { q[d] = b2f((unsigned short)q0[d]); q[8 + d] = b2f((unsigned short)q1[d]); }
  }
  __syncthreads();

  const int jbase = hf * 64;
  float p[64];
#pragma unroll
  for (int jj = 0; jj < 64; ++jj) {
    const float* kr = ks_[jbase + jj];
    float4 k0 = *(const float4*)&kr[0];
    float4 k1 = *(const float4*)&kr[4];
    float4 k2 = *(const float4*)&kr[8];
    float4 k3 = *(const float4*)&kr[12];
    float s = q[0]*k0.x + q[1]*k0.y + q[2]*k0.z + q[3]*k0.w
            + q[4]*k1.x + q[5]*k1.y + q[6]*k1.z + q[7]*k1.w
            + q[8]*k2.x + q[9]*k2.y + q[10]*k2.z + q[11]*k2.w
            + q[12]*k3.x + q[13]*k3.y + q[14]*k3.z + q[15]*k3.w;
    p[jj] = s * 0.25f;   // HS^-0.5
  }

  // causal softmax across the lane pair
  int nv = r - jbase + 1;           // #valid cols in this half
  if (nv < 0) nv = 0; if (nv > 64) nv = 64;
  float m = -3.0e38f;
#pragma unroll
  for (int jj = 0; jj < 64; ++jj) if (jj < nv) m = fmaxf(m, p[jj]);
  m = fmaxf(m, __shfl_xor(m, 1));
  float sum = 0.f;
#pragma unroll
  for (int jj = 0; jj < 64; ++jj) {
    float e = (jj < nv) ? __expf(p[jj] - m) : 0.f;
    p[jj] = e; sum += e;
  }
  sum += __shfl_xor(sum, 1);
  float inv = 1.f / sum;
#pragma unroll
  for (int jj = 0; jj < 64; ++jj) p[jj] *= inv;

  // O = P V (partials over this half's cols)
  float o[16] = {0.f};
#pragma unroll
  for (int jj = 0; jj < 64; ++jj) {
    const float* vr = vs_[jbase + jj];
    float4 v0 = *(const float4*)&vr[0];
    float4 v1 = *(const float4*)&vr[4];
    float4 v2 = *(const float4*)&vr[8];
    float4 v3 = *(const float4*)&vr[12];
    float pj = p[jj];
    o[0]  += pj * v0.x; o[1]  += pj * v0.y; o[2]  += pj * v0.z; o[3]  += pj * v0.w;
    o[4]  += pj * v1.x; o[5]  += pj * v1.y; o[6]  += pj * v1.z; o[7]  += pj * v1.w;
    o[8]  += pj * v2.x; o[9]  += pj * v2.y; o[10] += pj * v2.z; o[11] += pj * v2.w;
    o[12] += pj * v3.x; o[13] += pj * v3.y; o[14] += pj * v3.z; o[15] += pj * v3.w;
  }
#pragma unroll
  for (int d = 0; d < 16; ++d) o[d] += __shfl_xor(o[d], 1);

  // each half-thread writes its 8 output dims (static indexing via select)
  float sel[8];
#pragma unroll
  for (int j = 0; j < 8; ++j) sel[j] = hf ? o[8 + j] : o[j];
  short8 pk;
#pragma unroll
  for (int j = 0; j < 8; ++j) pk[j] = (short)f2bf(sel[j]);
  *(short8*)&aout[((size_t)(b * TT + r)) * CC + coff + hf * 8] = pk;
}

extern "C" void kernel_launch(void* const* d_in, const int* in_sizes, int n_in,
                              void* d_out, int out_size, void* d_ws, size_t ws_size,
                              hipStream_t stream) {
  const int*   idx  = (const int*)d_in[0];
  const float* tok  = (const float*)d_in[1];
  const float* pos  = (const float*)d_in[2];
  const float* Wq   = (const float*)d_in[3];
  const float* Wk   = (const float*)d_in[4];
  const float* Wv   = (const float*)d_in[5];
  const float* Wp   = (const float*)d_in[6];
  const float* bp   = (const float*)d_in[7];
  const float* W1   = (const float*)d_in[8];
  const float* b1   = (const float*)d_in[9];
  const float* W2   = (const float*)d_in[10];
  const float* b2   = (const float*)d_in[11];
  const float* ln1g = (const float*)d_in[12];
  const float* ln1b = (const float*)d_in[13];
  const float* ln2g = (const float*)d_in[14];
  const float* ln2b = (const float*)d_in[15];
  const float* lnfg = (const float*)d_in[16];
  const float* lnfb = (const float*)d_in[17];
  const float* Wlm  = (const float*)d_in[18];
  const float* blm  = (const float*)d_in[19];

  // workspace: x fp32 | h bf16 | qkv/ff union bf16 | packed weights bf16
  float* x = (float*)d_ws;
  unsigned short* h    = (unsigned short*)(x + (size_t)BT * CC);
  unsigned short* qkvb = h + (size_t)BT * CC;
  unsigned short* ffb  = qkvb;                              // union (disjoint lifetimes)
  unsigned short* wpk  = qkvb + (size_t)BT * FFD;           // FFD=384 covers 288 too
  // packed weight offsets (elements)
  const size_t OQKV = 0, OPRJ = 165888, OFF1 = 221184, OFF2 = 442368, OLM = 663552;

  pack_w<<<dim3(144, 25), 256, 0, stream>>>(Wq, Wk, Wv, Wp, W1, W2, Wlm, wpk);
  embed_kernel<<<BT * 24 / 256, 256, 0, stream>>>(idx, tok, pos, x);

  for (int l = 0; l < LL; ++l) {
    ln_kernel<<<BT / 8, 256, 0, stream>>>(x, h, ln1g + l * CC, ln1b + l * CC);
    mfma_gemm<96, 288, 288, false, false, false, true>
        <<<BT / 64, 256, 0, stream>>>(h, wpk + OQKV + (size_t)l * 27648, nullptr, nullptr, qkvb);
    attn_kernel<<<BB * HH, 256, 0, stream>>>(qkvb, h);
    mfma_gemm<96, 96, 96, true, false, true, false>
        <<<BT / 64, 256, 0, stream>>>(h, wpk + OPRJ + (size_t)l * 9216, bp + l * CC, x, x);
    ln_kernel<<<BT / 8, 256, 0, stream>>>(x, h, ln2g + l * CC, ln2b + l * CC);
    mfma_gemm<96, 384, 384, true, true, false, true>
        <<<BT / 64, 256, 0, stream>>>(h, wpk + OFF1 + (size_t)l * 36864, b1 + l * FFD, nullptr, ffb);
    mfma_gemm<384, 96, 96, true, false, true, false>
        <<<BT / 64, 256, 0, stream>>>(ffb, wpk + OFF2 + (size_t)l * 36864, b2 + l * CC, x, x);
  }

  ln_kernel<<<BT / 8, 256, 0, stream>>>(x, h, lnfg, lnfb);
  mfma_gemm<96, 80, 65, true, false, false, false>
      <<<BT / 64, 256, 0, stream>>>(h, wpk + OLM, blm, nullptr, (float*)d_out);
}

// Round 9
// 806.636 us; speedup vs baseline: 4.8912x; 1.8566x over previous
//
#include <hip/hip_runtime.h>
#include <hip/hip_bf16.h>

#define BB  512
#define TT  128
#define CC  96
#define HH  6
#define HSZ 16
#define LL  6
#define FFD 384
#define VV  65
#define BT  (BB * TT)   // 65536 rows

using short8  = __attribute__((ext_vector_type(8))) short;   // 8 bf16 (4 VGPRs)
using short4v = __attribute__((ext_vector_type(4))) short;   // 4 bf16
using f32x4   = __attribute__((ext_vector_type(4))) float;
using half4   = __attribute__((ext_vector_type(4))) _Float16;

static __device__ __forceinline__ unsigned short f2bf(float f) {
  union { float f; unsigned u; } v{f};
  unsigned r = (v.u + 0x7fff + ((v.u >> 16) & 1)) >> 16;   // RNE
  return (unsigned short)r;
}
static __device__ __forceinline__ float b2f(unsigned short h) {
  union { unsigned u; float f; } v{(unsigned)h << 16};
  return v.f;
}

// ---------------- embedding: x[b,t,:] = tok_emb[idx[b,t],:] + pos_emb[t,:] (fp32) -------
__global__ __launch_bounds__(256) void embed_kernel(
    const int* __restrict__ idx, const float* __restrict__ tok,
    const float* __restrict__ pos, float* __restrict__ x) {
  int gid = blockIdx.x * 256 + threadIdx.x;      // over BT*24 float4s
  int r = gid / 24, c4 = gid % 24;
  int t = r & (TT - 1);
  int token = idx[r];
  const float4 a = *(const float4*)&tok[token * CC + c4 * 4];
  const float4 p = *(const float4*)&pos[t * CC + c4 * 4];
  float4 o;
  o.x = a.x + p.x; o.y = a.y + p.y; o.z = a.z + p.z; o.w = a.w + p.w;
  *(float4*)&x[(size_t)r * CC + c4 * 4] = o;
}

// ---------------- layernorm fp32 in -> bf16 out: 32 lanes/row, 8 rows/block -------------
__global__ __launch_bounds__(256) void ln_kernel(
    const float* __restrict__ in, unsigned short* __restrict__ out,
    const float* __restrict__ g, const float* __restrict__ b) {
  int lane = threadIdx.x & 31;
  int r8 = threadIdx.x >> 5;
  size_t row = (size_t)blockIdx.x * 8 + r8;
  const float* p = in + row * CC;
  float v0 = p[lane], v1 = p[lane + 32], v2 = p[lane + 64];
  float s = v0 + v1 + v2;
  float s2 = v0 * v0 + v1 * v1 + v2 * v2;
#pragma unroll
  for (int m = 16; m; m >>= 1) {
    s  += __shfl_xor(s,  m, 32);
    s2 += __shfl_xor(s2, m, 32);
  }
  float mean = s * (1.f / 96.f);
  float var  = s2 * (1.f / 96.f) - mean * mean;
  float rs = rsqrtf(var + 1e-5f);
  unsigned short* q = out + row * CC;
  q[lane]      = f2bf((v0 - mean) * rs * g[lane]      + b[lane]);
  q[lane + 32] = f2bf((v1 - mean) * rs * g[lane + 32] + b[lane + 32]);
  q[lane + 64] = f2bf((v2 - mean) * rs * g[lane + 64] + b[lane + 64]);
}

// ---------------- weight pack: fp32 -> bf16 fragment-major [cb][ks][lane][8] ------------
// b_frag element j of lane l == B[k = ks*32 + (l>>4)*8 + j][n = cb*16 + (l&15)]
__global__ __launch_bounds__(256) void pack_w(
    const float* __restrict__ Wq, const float* __restrict__ Wk,
    const float* __restrict__ Wv, const float* __restrict__ Wp,
    const float* __restrict__ W1, const float* __restrict__ W2,
    const float* __restrict__ Wlm, unsigned short* __restrict__ out) {
  int job = blockIdx.y;
  int e = blockIdx.x * 256 + threadIdx.x;
  int K, sz; size_t obase;
  if (job < 6)       { K = 96;  sz = 27648; obase = (size_t)job * 27648; }
  else if (job < 12) { K = 96;  sz = 9216;  obase = 165888 + (size_t)(job - 6) * 9216; }
  else if (job < 18) { K = 96;  sz = 36864; obase = 221184 + (size_t)(job - 12) * 36864; }
  else if (job < 24) { K = 384; sz = 36864; obase = 442368 + (size_t)(job - 18) * 36864; }
  else               { K = 96;  sz = 7680;  obase = 663552; }
  if (e >= sz) return;
  int j = e & 7, lane = (e >> 3) & 63, rest = e >> 9;
  int KS = K / 32;
  int ks = rest % KS, cb = rest / KS;
  int k = ks * 32 + (lane >> 4) * 8 + j;
  int n = cb * 16 + (lane & 15);
  float val = 0.f;
  if (job < 6) {              // fused QKV, N=288: [H][C][HS] per source
    int src = n / 96, nn = n % 96;
    const float* W = (src == 0) ? Wq : (src == 1) ? Wk : Wv;
    val = W[((size_t)(job * 6 + (nn >> 4)) * 96 + k) * 16 + (nn & 15)];
  } else if (job < 12) {      // proj [96][96]
    val = Wp[(size_t)(job - 6) * 9216 + k * 96 + n];
  } else if (job < 18) {      // ff1 [96][384]
    val = W1[(size_t)(job - 12) * 36864 + k * 384 + n];
  } else if (job < 24) {      // ff2 [384][96]
    val = W2[(size_t)(job - 18) * 36864 + k * 96 + n];
  } else {                    // lm head [96][65] padded to N=80
    if (n < 65) val = Wlm[k * 65 + n];
  }
  out[obase + e] = f2bf(val);
}

// ---------------- MFMA GEMM: out[r][n] = act(sum_k A[r][k]*W[k][n] + bias) (+res) -------
// A: bf16 row-major [BT][K]. W: packed frags. 256 thr = 4 waves, each wave 16 rows.
template<int K, int N, int NS, bool BIAS, bool RELU, bool RES, bool OUTBF>
__global__ __launch_bounds__(256) void mfma_gemm(
    const unsigned short* __restrict__ A, const unsigned short* __restrict__ Wpk,
    const float* __restrict__ bias, const float* __restrict__ res, void* __restrict__ out) {
  constexpr int KS = K / 32;
  const int lane = threadIdx.x & 63;
  const int wave = threadIdx.x >> 6;
  const int r0 = blockIdx.x * 64 + wave * 16;
  const int c15 = lane & 15, kg = lane >> 4;
  short8 a[KS];
  const unsigned short* ap = A + (size_t)(r0 + c15) * K + kg * 8;
#pragma unroll
  for (int ks = 0; ks < KS; ++ks) a[ks] = *(const short8*)(ap + ks * 32);
  const short8* wf = (const short8*)Wpk;
#pragma unroll 1
  for (int cb = 0; cb < N / 16; ++cb) {
    f32x4 acc = {0.f, 0.f, 0.f, 0.f};
#pragma unroll
    for (int ks = 0; ks < KS; ++ks) {
      short8 b = wf[(cb * KS + ks) * 64 + lane];
      acc = __builtin_amdgcn_mfma_f32_16x16x32_bf16(a[ks], b, acc, 0, 0, 0);
    }
    int n = cb * 16 + c15;
#pragma unroll
    for (int i = 0; i < 4; ++i) {
      int row = r0 + kg * 4 + i;
      if (NS == N || n < NS) {
        float v = acc[i];
        if (BIAS) v += bias[n];
        if (RELU) v = fmaxf(v, 0.f);
        if (RES)  v += res[(size_t)row * NS + n];
        if (OUTBF) ((unsigned short*)out)[(size_t)row * NS + n] = f2bf(v);
        else       ((float*)out)[(size_t)row * NS + n] = v;
      }
    }
  }
}

// ---------------- MFMA attention: one block per (b,head), 4 waves ----------------------
// S^T = K.Q^T via mfma_f32_16x16x16f16  (contraction d=16, one MFMA per 16x16 tile).
// C-layout of S^T (col=q=lane&15, row=k=(lane>>4)*4+reg) == B-frag layout of the next
// MFMA, so softmax'd P^T feeds O^T = V^T.P^T with zero cross-lane movement.
// Wave w owns q-tiles {w, 7-w} (balanced causal work). K/V staged as f16 in LDS,
// stride-20 rows (conflict-free for b64 A-frag reads and V^T scalar reads).
__global__ __launch_bounds__(256) void attn_mfma(
    const unsigned short* __restrict__ qkv, unsigned short* __restrict__ aout) {
  const int b = blockIdx.x / HH, hd = blockIdx.x % HH;
  __shared__ _Float16 Ks[TT][20];   // K (f16); reused for O^T after barrier
  __shared__ _Float16 Vs[TT][20];
  const size_t base = (size_t)b * TT * 288 + hd * HSZ;   // qkv rows are [q|k|v] of 96 each
  const int t = threadIdx.x;
  const int r = t >> 1, part = t & 1;

  // ---- stage K,V rows, bf16 -> f16 (thread: one row, one 8-elem half) ----
  {
    const short8 k8 = *(const short8*)&qkv[base + (size_t)r * 288 + 96  + part * 8];
    const short8 v8 = *(const short8*)&qkv[base + (size_t)r * 288 + 192 + part * 8];
    half4 klo, khi, vlo, vhi;
#pragma unroll
    for (int j = 0; j < 4; ++j) {
      klo[j] = (_Float16)b2f((unsigned short)k8[j]);
      khi[j] = (_Float16)b2f((unsigned short)k8[4 + j]);
      vlo[j] = (_Float16)b2f((unsigned short)v8[j]);
      vhi[j] = (_Float16)b2f((unsigned short)v8[4 + j]);
    }
    *(half4*)&Ks[r][part * 8]     = klo;
    *(half4*)&Ks[r][part * 8 + 4] = khi;
    *(half4*)&Vs[r][part * 8]     = vlo;
    *(half4*)&Vs[r][part * 8 + 4] = vhi;
  }
  __syncthreads();

  const int lane = t & 63;
  const int w = t >> 6;
  const int q15 = lane & 15, g = lane >> 4;
  const int qt0 = w, qt1 = 7 - w;

  // ---- Q B-frags straight from global: B[d=(g*4+j)][q=q15] = Q[q][d] ----
  half4 bq[2];
  {
    const short4v qa = *(const short4v*)&qkv[base + (size_t)(qt0 * 16 + q15) * 288 + g * 4];
    const short4v qb = *(const short4v*)&qkv[base + (size_t)(qt1 * 16 + q15) * 288 + g * 4];
#pragma unroll
    for (int j = 0; j < 4; ++j) {
      bq[0][j] = (_Float16)b2f((unsigned short)qa[j]);
      bq[1][j] = (_Float16)b2f((unsigned short)qb[j]);
    }
  }

  // ---- K A-frags: A[m=k'=q15][d=g*4+j] ----
  half4 ak[8];
#pragma unroll
  for (int kt = 0; kt < 8; ++kt)
    ak[kt] = *(const half4*)&Ks[kt * 16 + q15][g * 4];

  // ---- S^T = K.Q^T : 16 MFMAs ----
  const f32x4 zero = {0.f, 0.f, 0.f, 0.f};
  f32x4 sx[2][8];
#pragma unroll
  for (int kt = 0; kt < 8; ++kt) {
    sx[0][kt] = __builtin_amdgcn_mfma_f32_16x16x16f16(ak[kt], bq[0], zero, 0, 0, 0);
    sx[1][kt] = __builtin_amdgcn_mfma_f32_16x16x16f16(ak[kt], bq[1], zero, 0, 0, 0);
  }

  // ---- causal mask + softmax over k (rows of S^T) + cvt to P^T B-frags ----
  half4 bp[2][8];
#pragma unroll
  for (int s = 0; s < 2; ++s) {
    const int qt = s ? qt1 : qt0;
    const int qg = qt * 16 + q15;          // global q row
    float mx = -3.0e38f;
#pragma unroll
    for (int kt = 0; kt < 8; ++kt)
#pragma unroll
      for (int i = 0; i < 4; ++i) {
        int kg = kt * 16 + g * 4 + i;
        float v = (kg <= qg) ? sx[s][kt][i] * 0.25f : -3.0e38f;   // scale = HS^-0.5
        sx[s][kt][i] = v;
        mx = fmaxf(mx, v);
      }
    mx = fmaxf(mx, __shfl_xor(mx, 16));
    mx = fmaxf(mx, __shfl_xor(mx, 32));
    float sum = 0.f;
#pragma unroll
    for (int kt = 0; kt < 8; ++kt)
#pragma unroll
      for (int i = 0; i < 4; ++i) {
        float p = __expf(sx[s][kt][i] - mx);
        sx[s][kt][i] = p;
        sum += p;
      }
    sum += __shfl_xor(sum, 16);
    sum += __shfl_xor(sum, 32);
    float inv = 1.f / sum;
#pragma unroll
    for (int kt = 0; kt < 8; ++kt)
#pragma unroll
      for (int i = 0; i < 4; ++i)
        bp[s][kt][i] = (_Float16)(sx[s][kt][i] * inv);
  }

  // ---- O^T = V^T.P^T : A[m=d=q15][k=g*4+j] = V[k][d]; 16 MFMAs ----
  f32x4 o0 = zero, o1 = zero;
#pragma unroll
  for (int kt = 0; kt < 8; ++kt) {
    half4 av;
#pragma unroll
    for (int j = 0; j < 4; ++j) av[j] = Vs[kt * 16 + g * 4 + j][q15];
    o0 = __builtin_amdgcn_mfma_f32_16x16x16f16(av, bp[0][kt], o0, 0, 0, 0);
    o1 = __builtin_amdgcn_mfma_f32_16x16x16f16(av, bp[1][kt], o1, 0, 0, 0);
  }

  // ---- bounce O^T through freed K-LDS for a coalesced bf16 write ----
  __syncthreads();   // all Ks reads happened before the MFMAs; safe to overwrite
  {
    half4 w0, w1;
#pragma unroll
    for (int i = 0; i < 4; ++i) { w0[i] = (_Float16)o0[i]; w1[i] = (_Float16)o1[i]; }
    *(half4*)&Ks[qt0 * 16 + q15][g * 4] = w0;   // Os[q][d]
    *(half4*)&Ks[qt1 * 16 + q15][g * 4] = w1;
  }
  __syncthreads();
  {
    const half4 a0 = *(const half4*)&Ks[r][part * 8];
    const half4 a1 = *(const half4*)&Ks[r][part * 8 + 4];
    short8 pk;
#pragma unroll
    for (int j = 0; j < 4; ++j) {
      pk[j]     = (short)f2bf((float)a0[j]);
      pk[4 + j] = (short)f2bf((float)a1[j]);
    }
    *(short8*)&aout[(size_t)(b * TT + r) * CC + hd * HSZ + part * 8] = pk;
  }
}

extern "C" void kernel_launch(void* const* d_in, const int* in_sizes, int n_in,
                              void* d_out, int out_size, void* d_ws, size_t ws_size,
                              hipStream_t stream) {
  const int*   idx  = (const int*)d_in[0];
  const float* tok  = (const float*)d_in[1];
  const float* pos  = (const float*)d_in[2];
  const float* Wq   = (const float*)d_in[3];
  const float* Wk   = (const float*)d_in[4];
  const float* Wv   = (const float*)d_in[5];
  const float* Wp   = (const float*)d_in[6];
  const float* bp   = (const float*)d_in[7];
  const float* W1   = (const float*)d_in[8];
  const float* b1   = (const float*)d_in[9];
  const float* W2   = (const float*)d_in[10];
  const float* b2   = (const float*)d_in[11];
  const float* ln1g = (const float*)d_in[12];
  const float* ln1b = (const float*)d_in[13];
  const float* ln2g = (const float*)d_in[14];
  const float* ln2b = (const float*)d_in[15];
  const float* lnfg = (const float*)d_in[16];
  const float* lnfb = (const float*)d_in[17];
  const float* Wlm  = (const float*)d_in[18];
  const float* blm  = (const float*)d_in[19];

  // workspace: x fp32 | h bf16 | qkv/ff union bf16 | packed weights bf16
  float* x = (float*)d_ws;
  unsigned short* h    = (unsigned short*)(x + (size_t)BT * CC);
  unsigned short* qkvb = h + (size_t)BT * CC;
  unsigned short* ffb  = qkvb;                              // union (disjoint lifetimes)
  unsigned short* wpk  = qkvb + (size_t)BT * FFD;           // FFD=384 covers 288 too
  // packed weight offsets (elements)
  const size_t OQKV = 0, OPRJ = 165888, OFF1 = 221184, OFF2 = 442368, OLM = 663552;

  pack_w<<<dim3(144, 25), 256, 0, stream>>>(Wq, Wk, Wv, Wp, W1, W2, Wlm, wpk);
  embed_kernel<<<BT * 24 / 256, 256, 0, stream>>>(idx, tok, pos, x);

  for (int l = 0; l < LL; ++l) {
    ln_kernel<<<BT / 8, 256, 0, stream>>>(x, h, ln1g + l * CC, ln1b + l * CC);
    mfma_gemm<96, 288, 288, false, false, false, true>
        <<<BT / 64, 256, 0, stream>>>(h, wpk + OQKV + (size_t)l * 27648, nullptr, nullptr, qkvb);
    attn_mfma<<<BB * HH, 256, 0, stream>>>(qkvb, h);
    mfma_gemm<96, 96, 96, true, false, true, false>
        <<<BT / 64, 256, 0, stream>>>(h, wpk + OPRJ + (size_t)l * 9216, bp + l * CC, x, x);
    ln_kernel<<<BT / 8, 256, 0, stream>>>(x, h, ln2g + l * CC, ln2b + l * CC);
    mfma_gemm<96, 384, 384, true, true, false, true>
        <<<BT / 64, 256, 0, stream>>>(h, wpk + OFF1 + (size_t)l * 36864, b1 + l * FFD, nullptr, ffb);
    mfma_gemm<384, 96, 96, true, false, true, false>
        <<<BT / 64, 256, 0, stream>>>(ffb, wpk + OFF2 + (size_t)l * 36864, b2 + l * CC, x, x);
  }

  ln_kernel<<<BT / 8, 256, 0, stream>>>(x, h, lnfg, lnfb);
  mfma_gemm<96, 80, 65, true, false, false, false>
      <<<BT / 64, 256, 0, stream>>>(h, wpk + OLM, blm, nullptr, (float*)d_out);
}

// Round 10
// 742.938 us; speedup vs baseline: 5.3106x; 1.0857x over previous
//
#include <hip/hip_runtime.h>
#include <hip/hip_bf16.h>

#define BB  512
#define TT  128
#define CC  96
#define HH  6
#define HSZ 16
#define LL  6
#define FFD 384
#define VV  65
#define BT  (BB * TT)   // 65536 rows

using short8  = __attribute__((ext_vector_type(8))) short;   // 8 bf16 (4 VGPRs)
using short4v = __attribute__((ext_vector_type(4))) short;   // 4 bf16
using f32x4   = __attribute__((ext_vector_type(4))) float;
using half4   = __attribute__((ext_vector_type(4))) _Float16;

static __device__ __forceinline__ unsigned short f2bf(float f) {
  union { float f; unsigned u; } v{f};
  unsigned r = (v.u + 0x7fff + ((v.u >> 16) & 1)) >> 16;   // RNE
  return (unsigned short)r;
}
static __device__ __forceinline__ float b2f(unsigned short h) {
  union { unsigned u; float f; } v{(unsigned)h << 16};
  return v.f;
}

// ---------------- embedding: x[b,t,:] = tok_emb[idx[b,t],:] + pos_emb[t,:] (fp32) -------
__global__ __launch_bounds__(256) void embed_kernel(
    const int* __restrict__ idx, const float* __restrict__ tok,
    const float* __restrict__ pos, float* __restrict__ x) {
  int gid = blockIdx.x * 256 + threadIdx.x;      // over BT*24 float4s
  int r = gid / 24, c4 = gid % 24;
  int t = r & (TT - 1);
  int token = idx[r];
  const float4 a = *(const float4*)&tok[token * CC + c4 * 4];
  const float4 p = *(const float4*)&pos[t * CC + c4 * 4];
  float4 o;
  o.x = a.x + p.x; o.y = a.y + p.y; o.z = a.z + p.z; o.w = a.w + p.w;
  *(float4*)&x[(size_t)r * CC + c4 * 4] = o;
}

// ---------------- weight pack: fp32 -> bf16 fragment-major [cb][ks][lane][8] ------------
// b_frag element j of lane l == B[k = ks*32 + (l>>4)*8 + j][n = cb*16 + (l&15)]
__global__ __launch_bounds__(256) void pack_w(
    const float* __restrict__ Wq, const float* __restrict__ Wk,
    const float* __restrict__ Wv, const float* __restrict__ Wp,
    const float* __restrict__ W1, const float* __restrict__ W2,
    const float* __restrict__ Wlm, unsigned short* __restrict__ out) {
  int job = blockIdx.y;
  int e = blockIdx.x * 256 + threadIdx.x;
  int K, sz; size_t obase;
  if (job < 6)       { K = 96;  sz = 27648; obase = (size_t)job * 27648; }
  else if (job < 12) { K = 96;  sz = 9216;  obase = 165888 + (size_t)(job - 6) * 9216; }
  else if (job < 18) { K = 96;  sz = 36864; obase = 221184 + (size_t)(job - 12) * 36864; }
  else if (job < 24) { K = 384; sz = 36864; obase = 442368 + (size_t)(job - 18) * 36864; }
  else               { K = 96;  sz = 7680;  obase = 663552; }
  if (e >= sz) return;
  int j = e & 7, lane = (e >> 3) & 63, rest = e >> 9;
  int KS = K / 32;
  int ks = rest % KS, cb = rest / KS;
  int k = ks * 32 + (lane >> 4) * 8 + j;
  int n = cb * 16 + (lane & 15);
  float val = 0.f;
  if (job < 6) {              // fused QKV, N=288: [H][C][HS] per source
    int src = n / 96, nn = n % 96;
    const float* W = (src == 0) ? Wq : (src == 1) ? Wk : Wv;
    val = W[((size_t)(job * 6 + (nn >> 4)) * 96 + k) * 16 + (nn & 15)];
  } else if (job < 12) {      // proj [96][96]
    val = Wp[(size_t)(job - 6) * 9216 + k * 96 + n];
  } else if (job < 18) {      // ff1 [96][384]
    val = W1[(size_t)(job - 12) * 36864 + k * 384 + n];
  } else if (job < 24) {      // ff2 [384][96]
    val = W2[(size_t)(job - 18) * 36864 + k * 96 + n];
  } else {                    // lm head [96][65] padded to N=80
    if (n < 65) val = Wlm[k * 65 + n];
  }
  out[obase + e] = f2bf(val);
}

// ---------------- MFMA GEMM: out[r][n] = act(sum_k A[r][k]*W[k][n] + bias) (+res) -------
// A: bf16 row-major [BT][K]. W: packed frags. 256 thr = 4 waves, each wave 16 rows.
template<int K, int N, int NS, bool BIAS, bool RELU, bool RES, bool OUTBF>
__global__ __launch_bounds__(256) void mfma_gemm(
    const unsigned short* __restrict__ A, const unsigned short* __restrict__ Wpk,
    const float* __restrict__ bias, const float* __restrict__ res, void* __restrict__ out) {
  constexpr int KS = K / 32;
  const int lane = threadIdx.x & 63;
  const int wave = threadIdx.x >> 6;
  const int r0 = blockIdx.x * 64 + wave * 16;
  const int c15 = lane & 15, kg = lane >> 4;
  short8 a[KS];
  const unsigned short* ap = A + (size_t)(r0 + c15) * K + kg * 8;
#pragma unroll
  for (int ks = 0; ks < KS; ++ks) a[ks] = *(const short8*)(ap + ks * 32);
  const short8* wf = (const short8*)Wpk;
#pragma unroll 1
  for (int cb = 0; cb < N / 16; ++cb) {
    f32x4 acc = {0.f, 0.f, 0.f, 0.f};
#pragma unroll
    for (int ks = 0; ks < KS; ++ks) {
      short8 b = wf[(cb * KS + ks) * 64 + lane];
      acc = __builtin_amdgcn_mfma_f32_16x16x32_bf16(a[ks], b, acc, 0, 0, 0);
    }
    int n = cb * 16 + c15;
#pragma unroll
    for (int i = 0; i < 4; ++i) {
      int row = r0 + kg * 4 + i;
      if (NS == N || n < NS) {
        float v = acc[i];
        if (BIAS) v += bias[n];
        if (RELU) v = fmaxf(v, 0.f);
        if (RES)  v += res[(size_t)row * NS + n];
        if (OUTBF) ((unsigned short*)out)[(size_t)row * NS + n] = f2bf(v);
        else       ((float*)out)[(size_t)row * NS + n] = v;
      }
    }
  }
}

// ---------------- fused LayerNorm + MFMA GEMM (K=96 always) ----------------------------
// Row r0+c15 is held by lanes {c15+16*kg}: shfl_xor(16/32) gives full-row mean/var.
// out[r][n] = act( sum_k LN(X)[r][k]*W[k][n] + bias[n] )
template<int N, int NS, bool BIAS, bool RELU, bool OUTBF>
__global__ __launch_bounds__(256) void ln_gemm(
    const float* __restrict__ X, const unsigned short* __restrict__ Wpk,
    const float* __restrict__ gamma, const float* __restrict__ beta,
    const float* __restrict__ bias, void* __restrict__ out) {
  const int lane = threadIdx.x & 63;
  const int wave = threadIdx.x >> 6;
  const int r0 = blockIdx.x * 64 + wave * 16;
  const int c15 = lane & 15, kg = lane >> 4;
  const float* xp = X + (size_t)(r0 + c15) * CC + kg * 8;
  float xv[24];
  float s = 0.f, s2 = 0.f;
#pragma unroll
  for (int ks = 0; ks < 3; ++ks) {
    float4 lo = *(const float4*)(xp + ks * 32);
    float4 hi = *(const float4*)(xp + ks * 32 + 4);
    xv[ks * 8 + 0] = lo.x; xv[ks * 8 + 1] = lo.y; xv[ks * 8 + 2] = lo.z; xv[ks * 8 + 3] = lo.w;
    xv[ks * 8 + 4] = hi.x; xv[ks * 8 + 5] = hi.y; xv[ks * 8 + 6] = hi.z; xv[ks * 8 + 7] = hi.w;
  }
#pragma unroll
  for (int i = 0; i < 24; ++i) { s += xv[i]; s2 += xv[i] * xv[i]; }
  s  += __shfl_xor(s, 16);  s  += __shfl_xor(s, 32);
  s2 += __shfl_xor(s2, 16); s2 += __shfl_xor(s2, 32);
  const float mean = s * (1.f / 96.f);
  const float rs = rsqrtf(s2 * (1.f / 96.f) - mean * mean + 1e-5f);
  short8 a[3];
#pragma unroll
  for (int ks = 0; ks < 3; ++ks) {
    const int kb = ks * 32 + kg * 8;
    float4 glo = *(const float4*)&gamma[kb];
    float4 ghi = *(const float4*)&gamma[kb + 4];
    float4 blo = *(const float4*)&beta[kb];
    float4 bhi = *(const float4*)&beta[kb + 4];
    const float gg[8] = {glo.x, glo.y, glo.z, glo.w, ghi.x, ghi.y, ghi.z, ghi.w};
    const float bb[8] = {blo.x, blo.y, blo.z, blo.w, bhi.x, bhi.y, bhi.z, bhi.w};
#pragma unroll
    for (int j = 0; j < 8; ++j)
      a[ks][j] = (short)f2bf((xv[ks * 8 + j] - mean) * rs * gg[j] + bb[j]);
  }
  const short8* wf = (const short8*)Wpk;
#pragma unroll 1
  for (int cb = 0; cb < N / 16; ++cb) {
    f32x4 acc = {0.f, 0.f, 0.f, 0.f};
#pragma unroll
    for (int ks = 0; ks < 3; ++ks) {
      short8 b = wf[(cb * 3 + ks) * 64 + lane];
      acc = __builtin_amdgcn_mfma_f32_16x16x32_bf16(a[ks], b, acc, 0, 0, 0);
    }
    int n = cb * 16 + c15;
#pragma unroll
    for (int i = 0; i < 4; ++i) {
      int row = r0 + kg * 4 + i;
      if (NS == N || n < NS) {
        float v = acc[i];
        if (BIAS) v += bias[n];
        if (RELU) v = fmaxf(v, 0.f);
        if (OUTBF) ((unsigned short*)out)[(size_t)row * NS + n] = f2bf(v);
        else       ((float*)out)[(size_t)row * NS + n] = v;
      }
    }
  }
}

// ---------------- MFMA attention: one block per (b,head), 4 waves ----------------------
// S^T = K.Q^T via mfma_f32_16x16x16f16  (contraction d=16, one MFMA per 16x16 tile).
// C-layout of S^T (col=q=lane&15, row=k=(lane>>4)*4+reg) == B-frag layout of the next
// MFMA, so softmax'd P^T feeds O^T = V^T.P^T with zero cross-lane movement.
__global__ __launch_bounds__(256) void attn_mfma(
    const unsigned short* __restrict__ qkv, unsigned short* __restrict__ aout) {
  const int b = blockIdx.x / HH, hd = blockIdx.x % HH;
  __shared__ _Float16 Ks[TT][20];   // K (f16); reused for O^T after barrier
  __shared__ _Float16 Vs[TT][20];
  const size_t base = (size_t)b * TT * 288 + hd * HSZ;   // qkv rows are [q|k|v] of 96 each
  const int t = threadIdx.x;
  const int r = t >> 1, part = t & 1;

  // ---- stage K,V rows, bf16 -> f16 (thread: one row, one 8-elem half) ----
  {
    const short8 k8 = *(const short8*)&qkv[base + (size_t)r * 288 + 96  + part * 8];
    const short8 v8 = *(const short8*)&qkv[base + (size_t)r * 288 + 192 + part * 8];
    half4 klo, khi, vlo, vhi;
#pragma unroll
    for (int j = 0; j < 4; ++j) {
      klo[j] = (_Float16)b2f((unsigned short)k8[j]);
      khi[j] = (_Float16)b2f((unsigned short)k8[4 + j]);
      vlo[j] = (_Float16)b2f((unsigned short)v8[j]);
      vhi[j] = (_Float16)b2f((unsigned short)v8[4 + j]);
    }
    *(half4*)&Ks[r][part * 8]     = klo;
    *(half4*)&Ks[r][part * 8 + 4] = khi;
    *(half4*)&Vs[r][part * 8]     = vlo;
    *(half4*)&Vs[r][part * 8 + 4] = vhi;
  }
  __syncthreads();

  const int lane = t & 63;
  const int w = t >> 6;
  const int q15 = lane & 15, g = lane >> 4;
  const int qt0 = w, qt1 = 7 - w;

  // ---- Q B-frags straight from global: B[d=(g*4+j)][q=q15] = Q[q][d] ----
  half4 bq[2];
  {
    const short4v qa = *(const short4v*)&qkv[base + (size_t)(qt0 * 16 + q15) * 288 + g * 4];
    const short4v qb = *(const short4v*)&qkv[base + (size_t)(qt1 * 16 + q15) * 288 + g * 4];
#pragma unroll
    for (int j = 0; j < 4; ++j) {
      bq[0][j] = (_Float16)b2f((unsigned short)qa[j]);
      bq[1][j] = (_Float16)b2f((unsigned short)qb[j]);
    }
  }

  // ---- K A-frags: A[m=k'=q15][d=g*4+j] ----
  half4 ak[8];
#pragma unroll
  for (int kt = 0; kt < 8; ++kt)
    ak[kt] = *(const half4*)&Ks[kt * 16 + q15][g * 4];

  // ---- S^T = K.Q^T : 16 MFMAs ----
  const f32x4 zero = {0.f, 0.f, 0.f, 0.f};
  f32x4 sx[2][8];
#pragma unroll
  for (int kt = 0; kt < 8; ++kt) {
    sx[0][kt] = __builtin_amdgcn_mfma_f32_16x16x16f16(ak[kt], bq[0], zero, 0, 0, 0);
    sx[1][kt] = __builtin_amdgcn_mfma_f32_16x16x16f16(ak[kt], bq[1], zero, 0, 0, 0);
  }

  // ---- causal mask + softmax over k (rows of S^T) + cvt to P^T B-frags ----
  half4 bp[2][8];
#pragma unroll
  for (int s = 0; s < 2; ++s) {
    const int qt = s ? qt1 : qt0;
    const int qg = qt * 16 + q15;          // global q row
    float mx = -3.0e38f;
#pragma unroll
    for (int kt = 0; kt < 8; ++kt)
#pragma unroll
      for (int i = 0; i < 4; ++i) {
        int kg = kt * 16 + g * 4 + i;
        float v = (kg <= qg) ? sx[s][kt][i] * 0.25f : -3.0e38f;   // scale = HS^-0.5
        sx[s][kt][i] = v;
        mx = fmaxf(mx, v);
      }
    mx = fmaxf(mx, __shfl_xor(mx, 16));
    mx = fmaxf(mx, __shfl_xor(mx, 32));
    float sum = 0.f;
#pragma unroll
    for (int kt = 0; kt < 8; ++kt)
#pragma unroll
      for (int i = 0; i < 4; ++i) {
        float p = __expf(sx[s][kt][i] - mx);
        sx[s][kt][i] = p;
        sum += p;
      }
    sum += __shfl_xor(sum, 16);
    sum += __shfl_xor(sum, 32);
    float inv = 1.f / sum;
#pragma unroll
    for (int kt = 0; kt < 8; ++kt)
#pragma unroll
      for (int i = 0; i < 4; ++i)
        bp[s][kt][i] = (_Float16)(sx[s][kt][i] * inv);
  }

  // ---- O^T = V^T.P^T : A[m=d=q15][k=g*4+j] = V[k][d]; 16 MFMAs ----
  f32x4 o0 = zero, o1 = zero;
#pragma unroll
  for (int kt = 0; kt < 8; ++kt) {
    half4 av;
#pragma unroll
    for (int j = 0; j < 4; ++j) av[j] = Vs[kt * 16 + g * 4 + j][q15];
    o0 = __builtin_amdgcn_mfma_f32_16x16x16f16(av, bp[0][kt], o0, 0, 0, 0);
    o1 = __builtin_amdgcn_mfma_f32_16x16x16f16(av, bp[1][kt], o1, 0, 0, 0);
  }

  // ---- bounce O^T through freed K-LDS for a coalesced bf16 write ----
  __syncthreads();   // all Ks reads happened before the MFMAs; safe to overwrite
  {
    half4 w0, w1;
#pragma unroll
    for (int i = 0; i < 4; ++i) { w0[i] = (_Float16)o0[i]; w1[i] = (_Float16)o1[i]; }
    *(half4*)&Ks[qt0 * 16 + q15][g * 4] = w0;   // Os[q][d]
    *(half4*)&Ks[qt1 * 16 + q15][g * 4] = w1;
  }
  __syncthreads();
  {
    const half4 a0 = *(const half4*)&Ks[r][part * 8];
    const half4 a1 = *(const half4*)&Ks[r][part * 8 + 4];
    short8 pk;
#pragma unroll
    for (int j = 0; j < 4; ++j) {
      pk[j]     = (short)f2bf((float)a0[j]);
      pk[4 + j] = (short)f2bf((float)a1[j]);
    }
    *(short8*)&aout[(size_t)(b * TT + r) * CC + hd * HSZ + part * 8] = pk;
  }
}

extern "C" void kernel_launch(void* const* d_in, const int* in_sizes, int n_in,
                              void* d_out, int out_size, void* d_ws, size_t ws_size,
                              hipStream_t stream) {
  const int*   idx  = (const int*)d_in[0];
  const float* tok  = (const float*)d_in[1];
  const float* pos  = (const float*)d_in[2];
  const float* Wq   = (const float*)d_in[3];
  const float* Wk   = (const float*)d_in[4];
  const float* Wv   = (const float*)d_in[5];
  const float* Wp   = (const float*)d_in[6];
  const float* bp   = (const float*)d_in[7];
  const float* W1   = (const float*)d_in[8];
  const float* b1   = (const float*)d_in[9];
  const float* W2   = (const float*)d_in[10];
  const float* b2   = (const float*)d_in[11];
  const float* ln1g = (const float*)d_in[12];
  const float* ln1b = (const float*)d_in[13];
  const float* ln2g = (const float*)d_in[14];
  const float* ln2b = (const float*)d_in[15];
  const float* lnfg = (const float*)d_in[16];
  const float* lnfb = (const float*)d_in[17];
  const float* Wlm  = (const float*)d_in[18];
  const float* blm  = (const float*)d_in[19];

  // workspace: x fp32 | h bf16 | qkv/ff union bf16 | packed weights bf16
  float* x = (float*)d_ws;
  unsigned short* h    = (unsigned short*)(x + (size_t)BT * CC);
  unsigned short* qkvb = h + (size_t)BT * CC;
  unsigned short* ffb  = qkvb;                              // union (disjoint lifetimes)
  unsigned short* wpk  = qkvb + (size_t)BT * FFD;           // FFD=384 covers 288 too
  // packed weight offsets (elements)
  const size_t OQKV = 0, OPRJ = 165888, OFF1 = 221184, OFF2 = 442368, OLM = 663552;

  pack_w<<<dim3(144, 25), 256, 0, stream>>>(Wq, Wk, Wv, Wp, W1, W2, Wlm, wpk);
  embed_kernel<<<BT * 24 / 256, 256, 0, stream>>>(idx, tok, pos, x);

  for (int l = 0; l < LL; ++l) {
    ln_gemm<288, 288, false, false, true>
        <<<BT / 64, 256, 0, stream>>>(x, wpk + OQKV + (size_t)l * 27648,
                                      ln1g + l * CC, ln1b + l * CC, nullptr, qkvb);
    attn_mfma<<<BB * HH, 256, 0, stream>>>(qkvb, h);
    mfma_gemm<96, 96, 96, true, false, true, false>
        <<<BT / 64, 256, 0, stream>>>(h, wpk + OPRJ + (size_t)l * 9216, bp + l * CC, x, x);
    ln_gemm<384, 384, true, true, true>
        <<<BT / 64, 256, 0, stream>>>(x, wpk + OFF1 + (size_t)l * 36864,
                                      ln2g + l * CC, ln2b + l * CC, b1 + l * FFD, ffb);
    mfma_gemm<384, 96, 96, true, false, true, false>
        <<<BT / 64, 256, 0, stream>>>(ffb, wpk + OFF2 + (size_t)l * 36864, b2 + l * CC, x, x);
  }

  ln_gemm<80, 65, true, false, false>
      <<<BT / 64, 256, 0, stream>>>(x, wpk + OLM, lnfg, lnfb, blm, (float*)d_out);
}